// Round 13
// baseline (177.100 us; speedup 1.0000x reference)
//
#include <hip/hip_runtime.h>
#include <hip/hip_fp16.h>

#define N_NODES 10000
#define BATCH   8
#define IN_SZ   64
#define UNITS   64
#define ROW_U   256            // uints per f16 row (512 f16 = 4 stripes of 64)
#define RCAP    96             // fixed per-row edge capacity (P(deg>96) ~ 1e-18)
#define STR     (N_NODES * 64) // uints per stripe (640,000)

typedef unsigned int uint;
typedef unsigned short ushort;
typedef __attribute__((ext_vector_type(8))) _Float16 half8;
typedef __attribute__((ext_vector_type(4))) float float4v;
typedef __attribute__((ext_vector_type(4))) uint uint4v;
typedef __attribute__((ext_vector_type(2))) uint uint2v;

// ---- numeric helpers -------------------------------------------------------
__device__ inline uint f2bf_bits(float f) {
    uint u = __float_as_uint(f);
    uint r = ((u >> 16) & 1u) + 0x7FFFu;
    return (u + r) >> 16;
}
__device__ inline uint pack2h(float a, float b) {
    return (uint)__half_as_ushort(__float2half(a)) |
           ((uint)__half_as_ushort(__float2half(b)) << 16);
}
__device__ inline float h_lo(uint u) {
    return __half2float(__ushort_as_half((ushort)(u & 0xFFFFu)));
}
__device__ inline float h_hi(uint u) {
    return __half2float(__ushort_as_half((ushort)(u >> 16)));
}

// ---------------------------------------------------------------------------
// EVIDENCE LEDGER (r1..r12):
//   F = 75.1us fixed harness; c ~= 11.5us per dispatch-gap [r10 CREP probe]
//   Steady work {T ~9, S1 10.6, S2 9.5, C ~6}, each near traffic floor.
//   r8 readlane edges WIN; r11 nt-strip + W-prepack WIN; r12 memset-kill WIN
//   (162.92). r7 fused S2+C LOST because waves had 8 SERIAL spmm tasks
//   (TLP collapse), not because of fusion per se.
// THIS ROUND: dispatches 4 -> 3. Re-do the S2+C fusion with correct geometry:
//   block = (16-node tile, stripe q), 1024 thr = 16 waves, ONE spmm row-task
//   per wave (40000 wave-tasks == standalone), __launch_bounds__(1024,8) ->
//   2 blocks/CU = 32 waves/CU (full). x2 tile in LDS only (x2 buffer gone).
//   Phase 2: 8 waves x one (batch, ut) 16x16 MFMA tile, W from prepacked wt.
// Cursor lifecycle (no combine dispatch to reset it): spmm1 snapshots
//   cnts[row] (4 dup same-value writers, benign); fused kernel reads cnts
//   only, so it can reset cursor[row] = V for no-repoison replays.
// ---------------------------------------------------------------------------

// ---------------------------------------------------------------------------
// k_transpose_scatter: UNCHANGED r12 body. Grid <<<5000, 256>>>.
// ---------------------------------------------------------------------------
__global__ __launch_bounds__(256) void k_transpose_scatter(
    const float4v* __restrict__ in4, uint* __restrict__ x0,
    const int* __restrict__ rows, const int* __restrict__ cols,
    const float* __restrict__ vals, uint* __restrict__ cursor,
    uint* __restrict__ edges, const float* __restrict__ W,
    ushort* __restrict__ wt, int nnz) {
    int gid = blockIdx.x * 256 + threadIdx.x;      // 1,280,000 total
    uint V = cursor[N_NODES];           // uniform base (poison or V-reset)
    if (gid < nnz) {
        int  r   = rows[gid];
        uint pos = atomicAdd(&cursor[r], 1u) - V;   // slot 0..deg-1, wrap-safe
        edges[r * RCAP + pos] = (uint)cols[gid] | (f2bf_bits(vals[gid]) << 16);
    }
    if (gid < 192 * 64) {               // one-time W prepack (sWt-linear)
        int u   = gid / 192;
        int col = gid - u * 192;        // = m*64 + i
        int m   = col >> 6, i = col & 63;
        wt[gid] = (ushort)__half_as_ushort(__float2half(W[(i * 3 + m) * 64 + u]));
    }
    int i4 = gid & 15;          // 4-channel chunk
    int b  = (gid >> 4) & 7;    // batch
    int n  = gid >> 7;          // node
    float4v v = __builtin_nontemporal_load(
        &in4[((size_t)b * N_NODES + n) * 16 + i4]);
    int c_u = b * 32 + i4 * 2;  // uint index within 256-uint row
    int q   = c_u >> 6;         // stripe (= b>>1)
    uint2v pk;
    pk.x = pack2h(v.x, v.y);
    pk.y = pack2h(v.z, v.w);
    *(uint2v*)(x0 + (size_t)q * STR + (size_t)n * 64 + (c_u & 63)) = pk;
}

// ---- spmm inner machinery (r8, proven) -------------------------------------
#define READE(EP, KB)                                                         \
    {                                                                         \
        uint _es = ((KB) < 8) ? erec : erec2;                                 \
        int  _i0 = (((KB) * 8) & 63);                                         \
        _Pragma("unroll") for (int jj = 0; jj < 8; ++jj)                      \
            EP[jj] = __builtin_amdgcn_readlane(_es, _i0 + jj);                \
    }

#define GATHERX(XR, EP)                                                       \
    _Pragma("unroll") for (int jj = 0; jj < 8; ++jj) {                        \
        uint c = EP[jj] & 0x3FFFu;                                            \
        if (c > N_NODES - 1) c = N_NODES - 1; /* s_min (garbage slots) */     \
        XR[jj] = xq[c * 64u + lane];          /* SALU idx + saddr gather */   \
    }

#define FMA8(EP, XR)                                                          \
    _Pragma("unroll") for (int jj = 0; jj < 8; ++jj) {                        \
        float vj = __uint_as_float(EP[jj] & 0xFFFF0000u); /* SALU decode */   \
        a0 += vj * h_lo(XR[jj]); /* v_fma_mix_f32 */                          \
        a1 += vj * h_hi(XR[jj]); /* v_fma_mix_f32 */                          \
    }

#define EDGE_PIPELINE()                                                       \
    uint epA[8], epB[8], xA[8], xB[8];                                        \
    READE(epA, 0);                                                            \
    GATHERX(xA, epA);                                                         \
    int k = 0;                                                                \
    for (; k + 2 <= nblk; k += 2) {                                           \
        READE(epB, k + 1);                                                    \
        GATHERX(xB, epB);                                                     \
        FMA8(epA, xA);                                                        \
        if (k + 2 < nblk) {                                                   \
            READE(epA, k + 2);                                                \
            GATHERX(xA, epA);                                                 \
        }                                                                     \
        FMA8(epB, xB);                                                        \
    }                                                                         \
    if (k < nblk) FMA8(epA, xA);

// ---------------------------------------------------------------------------
// k_spmm (spmm1 only): r12 body, xsub/scale dropped; additionally snapshots
// cnts[row] (4 duplicate same-value writers -> benign) for the fused kernel.
// Grid <<<N_NODES, 256>>>; stripe q = (L&7)>>1 pinned to XCD pair {2q,2q+1}.
// ---------------------------------------------------------------------------
__global__ __launch_bounds__(256) void k_spmm(const uint* __restrict__ cursor,
                                              int* __restrict__ cnts,
                                              const uint* __restrict__ edges,
                                              const uint* __restrict__ xin,
                                              uint* __restrict__ xout) {
    int L    = blockIdx.x;              // 10000 blocks
    int q    = (L & 7) >> 1;            // stripe pinned to XCD pair {2q,2q+1}
    int rb   = ((L >> 3) << 1) | (L & 1);   // 0..2499, bijective per stripe
    int wave = threadIdx.x >> 6;
    uint lane = threadIdx.x & 63;
    int row  = rb * 4 + wave;

    const uint* xq = xin;               // spmm1 input = x0, stripe q
    xq += (size_t)q * STR;
    int base = row * RCAP;
    uint V   = cursor[N_NODES];
    int cnt  = (int)__builtin_amdgcn_readfirstlane(cursor[row] - V);
    if (lane == 0) cnts[row] = cnt;     // snapshot for fused spmm2+combine
    int nblk = (cnt + 7) >> 3;          // >= 1 (diagonal guarantees cnt >= 1)

    uint erec = edges[base + (int)lane];
    if ((int)lane >= cnt) erec &= 0x3FFFu;          // v_cndmask
    uint erec2 = 0;
    if (cnt > 64) {                                  // uniform branch, rare
        erec2 = edges[base + 64 + (int)lane];
        if ((int)lane + 64 >= cnt) erec2 &= 0x3FFFu;
    }

    float a0 = 0.f, a1 = 0.f;
    EDGE_PIPELINE();

    // plain store: keep the line L2-resident for spmm2 gathers / combine
    xout[(size_t)q * STR + (size_t)row * 64 + lane] = pack2h(a0, a1);
}

// ---------------------------------------------------------------------------
// k_spmm2_combine: block = (16-node tile mi16, stripe q), 1024 thr = 16 waves.
// Phase 1: wave w computes spmm2 row n0+w (ONE task/wave == standalone TLP),
//          x2 value -> LDS x2L[w][lane] (pad 68: 2-way LDS conflicts = free).
//          Resets cursor[row] = V (fused reads cnts, never cursor[row]).
// Phase 2: waves 0..7: b = 2q + (w>>2), ut = w&3 -> one 16x16 MFMA tile.
//          af mats 0,1 from global x0/x1 (XCD-pinned), mat 2 from LDS,
//          W fragments direct from prepacked wt (6 loads/wave, L2-broadcast).
// Grid <<<2504, 1024>>> (4 idle); 625*16 = 10000 exactly -> no row clamps.
// __launch_bounds__(1024, 8): VGPR<=64 -> 2 blocks/CU = 32 waves/CU (full).
// ---------------------------------------------------------------------------
__global__ __launch_bounds__(1024, 8) void k_spmm2_combine(
    uint* __restrict__ cursor, const int* __restrict__ cnts,
    const uint* __restrict__ edges,
    const uint* __restrict__ x0, const uint* __restrict__ x1,
    const ushort* __restrict__ wt, const float* __restrict__ bias,
    float* __restrict__ out) {
    __shared__ uint x2L[16][68];       // 4.35 KB
    int t    = threadIdx.x;
    int w    = t >> 6;
    uint lane = t & 63;
    int L    = blockIdx.x;
    int q    = (L & 7) >> 1;           // stripe pinned to XCD pair {2q,2q+1}
    int mi16 = ((L >> 3) << 1) | (L & 1);   // 0..625
    if (mi16 >= 625) return;           // whole block exits (no barrier issue)
    int n0   = mi16 * 16;

    // ---- phase 1: spmm2 row n0+w -> LDS ------------------------------------
    {
        int row  = n0 + w;
        const uint* xq = x1 + (size_t)q * STR;
        int base = row * RCAP;
        uint V   = cursor[N_NODES];
        int cnt  = __builtin_amdgcn_readfirstlane(cnts[row]);
        if (lane == 0) cursor[row] = V;    // reset for next no-poison replay
        int nblk = (cnt + 7) >> 3;

        uint erec = edges[base + (int)lane];
        if ((int)lane >= cnt) erec &= 0x3FFFu;
        uint erec2 = 0;
        if (cnt > 64) {
            erec2 = edges[base + 64 + (int)lane];
            if ((int)lane + 64 >= cnt) erec2 &= 0x3FFFu;
        }
        uint sx = x0[(size_t)q * STR + (size_t)row * 64 + lane];

        float a0 = 0.f, a1 = 0.f;
        EDGE_PIPELINE();
        x2L[w][lane] = pack2h(2.f * a0 - h_lo(sx), 2.f * a1 - h_hi(sx));
    }
    __syncthreads();

    // ---- phase 2: combine, 8 waves x (batch, ut) ---------------------------
    if (w < 8) {
        int mrow = lane & 15, quad = lane >> 4;
        int b  = 2 * q + (w >> 2);     // batch; b>>1 == q
        int ut = w & 3;
        int an = n0 + mrow;            // < 10000 always (625*16 exact)

        const uint* xsg[2] = {x0, x1};
        half8 af[6];
#pragma unroll
        for (int kb = 0; kb < 4; ++kb) {
            int c_u = b * 32 + (kb & 1) * 16 + quad * 4;
            af[kb] = *(const half8*)(xsg[kb >> 1] + (size_t)q * STR +
                                     (size_t)an * 64 + (c_u & 63));
        }
#pragma unroll
        for (int kb = 4; kb < 6; ++kb) {
            int c_u = b * 32 + (kb & 1) * 16 + quad * 4;
            af[kb] = *(const half8*)&x2L[mrow][c_u & 63];
        }

        float4v acc = (float4v){0.f, 0.f, 0.f, 0.f};
#pragma unroll
        for (int kb = 0; kb < 6; ++kb) {
            half8 bf = *(const half8*)&wt[(size_t)(ut * 16 + mrow) * 192 +
                                          kb * 32 + quad * 8];
            acc = __builtin_amdgcn_mfma_f32_16x16x32_f16(af[kb], bf, acc,
                                                         0, 0, 0);
        }

        float bv = bias[ut * 16 + mrow];
        int u = ut * 16 + mrow;
#pragma unroll
        for (int r = 0; r < 4; ++r) {
            int n = n0 + quad * 4 + r;
            __builtin_nontemporal_store(acc[r] + bv,
                &out[((size_t)b * N_NODES + n) * UNITS + u]);
        }
    }
}

// ---------------------------------------------------------------------------
extern "C" void kernel_launch(void* const* d_in, const int* in_sizes, int n_in,
                              void* d_out, int out_size, void* d_ws, size_t ws_size,
                              hipStream_t stream) {
    const float* inputs = (const float*)d_in[0];
    const int*   rows   = (const int*)d_in[1];
    const int*   cols   = (const int*)d_in[2];
    const float* vals   = (const float*)d_in[3];
    const float* W      = (const float*)d_in[4];
    const float* bias   = (const float*)d_in[5];
    float*       out    = (float*)d_out;
    int nnz = in_sizes[1];

    char* p = (char*)d_ws;
    auto alloc = [&](size_t bytes) {
        char* r = p;
        p += (bytes + 255) & ~(size_t)255;
        return r;
    };
    uint*   x0     = (uint*)alloc(sizeof(uint) * (size_t)N_NODES * ROW_U);
    uint*   x1     = (uint*)alloc(sizeof(uint) * (size_t)N_NODES * ROW_U);
    uint*   cursor = (uint*)alloc(sizeof(uint) * (N_NODES + 64)); // +sentinel
    int*    cnts   = (int*)alloc(sizeof(int) * (N_NODES + 64));
    // +128 uints pad: erec2 read (base+64+lane) of the last row stays in-bounds
    uint*   edges  = (uint*)alloc(sizeof(uint) * ((size_t)N_NODES * RCAP + 128));
    ushort* wt     = (ushort*)alloc(sizeof(ushort) * 192 * 64);   // 24 KB

    // 3 dispatches: poison-base bucketing (V = cursor[N_NODES]); spmm1
    // snapshots cnts; fused spmm2+combine resets cursor rows to V.
    k_transpose_scatter<<<5000, 256, 0, stream>>>(
        (const float4v*)inputs, x0, rows, cols, vals, cursor, edges, W, wt,
        nnz);
    k_spmm<<<N_NODES, 256, 0, stream>>>(cursor, cnts, edges, x0, x1);
    k_spmm2_combine<<<2504, 1024, 0, stream>>>(cursor, cnts, edges, x0, x1,
                                               wt, bias, out);
}

// Round 14
// 170.249 us; speedup vs baseline: 1.0402x; 1.0402x over previous
//
#include <hip/hip_runtime.h>
#include <hip/hip_fp16.h>

#define N_NODES 10000
#define BATCH   8
#define IN_SZ   64
#define UNITS   64
#define ROW_U   256            // uints per f16 row (512 f16 = 4 stripes of 64)
#define RCAP    96             // fixed per-row edge capacity (P(deg>96) ~ 1e-18)
#define STR     (N_NODES * 64) // uints per stripe (640,000)

typedef unsigned int uint;
typedef unsigned short ushort;
typedef __attribute__((ext_vector_type(8))) _Float16 half8;
typedef __attribute__((ext_vector_type(4))) float float4v;
typedef __attribute__((ext_vector_type(4))) uint uint4v;
typedef __attribute__((ext_vector_type(2))) uint uint2v;

// ---- numeric helpers -------------------------------------------------------
__device__ inline uint f2bf_bits(float f) {
    uint u = __float_as_uint(f);
    uint r = ((u >> 16) & 1u) + 0x7FFFu;
    return (u + r) >> 16;
}
__device__ inline uint pack2h(float a, float b) {
    return (uint)__half_as_ushort(__float2half(a)) |
           ((uint)__half_as_ushort(__float2half(b)) << 16);
}
__device__ inline float h_lo(uint u) {
    return __half2float(__ushort_as_half((ushort)(u & 0xFFFFu)));
}
__device__ inline float h_hi(uint u) {
    return __half2float(__ushort_as_half((ushort)(u >> 16)));
}

// ---------------------------------------------------------------------------
// EVIDENCE LEDGER (r1..r13):
//   F = 75.1us fixed harness; per-dispatch ramp/drain+gap ~= 11-14us.
//   Steady {T ~8, S1 10.6, S2 9.5, C ~6} each near traffic floor [r10 PMC].
//   WINS: r8 readlane edges; r11 nt-strip + W-prepack; r12 memset-kill
//   (162.92 best). LOSSES: r3 persistent (spin storm), r7 fused S2C (53.2,
//   8 serial rows/wave), r9 no-LDS combine (+3.2), r13 fused S2C RETRY
//   (52.8: launch_bounds(1024,8) -> VGPR=32 -> EDGE_PIPELINE serialized;
//   16-wave barrier couples max of 16 variable-degree tasks). Two fusion
//   geometries, same 53us wall => fusion axis CLOSED.
// THIS ROUND: r12 structure + 2-ROW spmm waves. spmm wall (25.3) >> steady
//   (10.6) means latency/queue-bound across ~5 block-rounds; doubling MLP
//   (16 gathers in flight/wave, 5000 blocks, ~2.5 rounds) attacks the wall.
//   Unified masking (erec val-halves pre-zeroed past cnt) lets both rows run
//   to nblk=max with zero per-row control flow. VGPR ~60 <= 64 -> 8 blk/CU.
// ---------------------------------------------------------------------------

// ---------------------------------------------------------------------------
// k_transpose_scatter: UNCHANGED r12 body. Grid <<<5000, 256>>>.
// ---------------------------------------------------------------------------
__global__ __launch_bounds__(256) void k_transpose_scatter(
    const float4v* __restrict__ in4, uint* __restrict__ x0,
    const int* __restrict__ rows, const int* __restrict__ cols,
    const float* __restrict__ vals, uint* __restrict__ cursor,
    uint* __restrict__ edges, const float* __restrict__ W,
    ushort* __restrict__ wt, int nnz) {
    int gid = blockIdx.x * 256 + threadIdx.x;      // 1,280,000 total
    uint V = cursor[N_NODES];           // uniform base (poison or 0 on replay)
    if (gid < nnz) {
        int  r   = rows[gid];
        uint pos = atomicAdd(&cursor[r], 1u) - V;   // slot 0..deg-1, wrap-safe
        edges[r * RCAP + pos] = (uint)cols[gid] | (f2bf_bits(vals[gid]) << 16);
    }
    if (gid < 192 * 64) {               // one-time W prepack (sWt-linear)
        int u   = gid / 192;
        int col = gid - u * 192;        // = m*64 + i
        int m   = col >> 6, i = col & 63;
        wt[gid] = (ushort)__half_as_ushort(__float2half(W[(i * 3 + m) * 64 + u]));
    }
    int i4 = gid & 15;          // 4-channel chunk
    int b  = (gid >> 4) & 7;    // batch
    int n  = gid >> 7;          // node
    float4v v = __builtin_nontemporal_load(
        &in4[((size_t)b * N_NODES + n) * 16 + i4]);
    int c_u = b * 32 + i4 * 2;  // uint index within 256-uint row
    int q   = c_u >> 6;         // stripe (= b>>1)
    uint2v pk;
    pk.x = pack2h(v.x, v.y);
    pk.y = pack2h(v.z, v.w);
    *(uint2v*)(x0 + (size_t)q * STR + (size_t)n * 64 + (c_u & 63)) = pk;
}

// ---- spmm inner machinery: 2-row per-wave variants --------------------------
// Edge block KB of row with record regs (ES: edges 0..63, ESB: 64..95).
// ep values are wave-uniform (readlane -> SGPR); masking already applied.
#define READE2(EP, ES, ESB, KB)                                               \
    {                                                                         \
        uint _es = ((KB) < 8) ? (ES) : (ESB);                                 \
        int  _i0 = (((KB) * 8) & 63);                                         \
        _Pragma("unroll") for (int jj = 0; jj < 8; ++jj)                      \
            EP[jj] = __builtin_amdgcn_readlane(_es, _i0 + jj);                \
    }

#define GATHERX(XR, EP)                                                       \
    _Pragma("unroll") for (int jj = 0; jj < 8; ++jj) {                        \
        uint c = EP[jj] & 0x3FFFu;                                            \
        if (c > N_NODES - 1) c = N_NODES - 1; /* s_min (garbage slots) */     \
        XR[jj] = xq[c * 64u + lane];          /* SALU idx + saddr gather */   \
    }

#define FMA8R(EP, XR, A0, A1)                                                 \
    _Pragma("unroll") for (int jj = 0; jj < 8; ++jj) {                        \
        float vj = __uint_as_float(EP[jj] & 0xFFFF0000u); /* SALU decode */   \
        A0 += vj * h_lo(XR[jj]); /* v_fma_mix_f32 */                          \
        A1 += vj * h_hi(XR[jj]); /* v_fma_mix_f32 */                          \
    }

// ---------------------------------------------------------------------------
// k_spmm: one WAVE per TWO adjacent (row, stripe) tasks -> 16 gathers in
// flight (2x MLP), 5000 blocks (~2.5 block-rounds vs ~5). Both rows run the
// unified pipeline to nblk = max(nblk0, nblk1); rows past their own cnt
// contribute exactly +0.0 (val-halves pre-zeroed). Grid <<<5000, 256>>>;
// stripe q = (L&7)>>1 pinned to XCD pair {2q,2q+1}.
// ---------------------------------------------------------------------------
__global__ __launch_bounds__(256) void k_spmm(const uint* __restrict__ cursor,
                                              const uint* __restrict__ edges,
                                              const uint* __restrict__ xin,
                                              uint* __restrict__ xout,
                                              const uint* __restrict__ xsub,
                                              float scale) {
    int L    = blockIdx.x;              // 5000 blocks
    int q    = (L & 7) >> 1;            // stripe pinned to XCD pair {2q,2q+1}
    int rb   = ((L >> 3) << 1) | (L & 1);   // 0..1249, bijective per stripe
    int wave = threadIdx.x >> 6;
    uint lane = threadIdx.x & 63;
    int row0 = rb * 8 + wave * 2;       // rows row0, row0+1

    const uint* xq = xin + (size_t)q * STR;
    uint V     = cursor[N_NODES];
    int  base0 = row0 * RCAP;
    int  base1 = base0 + RCAP;
    int  cnt0  = (int)__builtin_amdgcn_readfirstlane(cursor[row0] - V);
    int  cnt1  = (int)__builtin_amdgcn_readfirstlane(cursor[row0 + 1] - V);
    int  cmax  = cnt0 > cnt1 ? cnt0 : cnt1;
    int  nblk  = (cmax + 7) >> 3;       // >= 1 (diagonal guarantees cnt >= 1)

    uint erec0 = edges[base0 + (int)lane];
    if ((int)lane >= cnt0) erec0 &= 0x3FFFu;        // v_cndmask
    uint erec1 = edges[base1 + (int)lane];
    if ((int)lane >= cnt1) erec1 &= 0x3FFFu;
    uint erec0b = 0, erec1b = 0;
    if (cmax > 64) {                                 // uniform branch, rare
        erec0b = edges[base0 + 64 + (int)lane];
        if ((int)lane + 64 >= cnt0) erec0b &= 0x3FFFu;
        erec1b = edges[base1 + 64 + (int)lane];
        if ((int)lane + 64 >= cnt1) erec1b &= 0x3FFFu;
    }

    uint sx0 = 0, sx1 = 0;
    if (xsub) {
        sx0 = xsub[(size_t)q * STR + (size_t)row0 * 64 + lane];
        sx1 = xsub[(size_t)q * STR + (size_t)(row0 + 1) * 64 + lane];
    }

    float a00 = 0.f, a01 = 0.f, a10 = 0.f, a11 = 0.f;
    uint epA0[8], epB0[8], xA0[8], xB0[8];
    uint epA1[8], epB1[8], xA1[8], xB1[8];
    READE2(epA0, erec0, erec0b, 0);
    GATHERX(xA0, epA0);
    READE2(epA1, erec1, erec1b, 0);
    GATHERX(xA1, epA1);                 // 16 gathers in flight
    int k = 0;
    for (; k + 2 <= nblk; k += 2) {
        READE2(epB0, erec0, erec0b, k + 1);
        GATHERX(xB0, epB0);
        READE2(epB1, erec1, erec1b, k + 1);
        GATHERX(xB1, epB1);
        FMA8R(epA0, xA0, a00, a01);
        FMA8R(epA1, xA1, a10, a11);
        if (k + 2 < nblk) {
            READE2(epA0, erec0, erec0b, k + 2);
            GATHERX(xA0, epA0);
            READE2(epA1, erec1, erec1b, k + 2);
            GATHERX(xA1, epA1);
        }
        FMA8R(epB0, xB0, a00, a01);
        FMA8R(epB1, xB1, a10, a11);
    }
    if (k < nblk) {
        FMA8R(epA0, xA0, a00, a01);
        FMA8R(epA1, xA1, a10, a11);
    }

    float o00 = scale * a00, o01 = scale * a01;
    float o10 = scale * a10, o11 = scale * a11;
    if (xsub) {
        o00 -= h_lo(sx0); o01 -= h_hi(sx0);
        o10 -= h_lo(sx1); o11 -= h_hi(sx1);
    }
    // plain stores: keep lines L2-resident for spmm2 gathers / combine
    xout[(size_t)q * STR + (size_t)row0 * 64 + lane]       = pack2h(o00, o01);
    xout[(size_t)q * STR + (size_t)(row0 + 1) * 64 + lane] = pack2h(o10, o11);
}

// ---------------------------------------------------------------------------
// k_combine (MFMA f16): UNCHANGED r12 body (LDS-staged W via b128 copies from
// prepacked wt; plain af loads; cursor re-zero for no-poison replays).
// Grid <<<157*8, 256>>>; b = L&7 pins batch -> stripe q=b>>1.
// ---------------------------------------------------------------------------
__global__ __launch_bounds__(256) void k_combine(const uint* __restrict__ x0,
                                                 const uint* __restrict__ x1,
                                                 const uint* __restrict__ x2,
                                                 const ushort* __restrict__ wt,
                                                 const float* __restrict__ bias,
                                                 uint* __restrict__ cursor,
                                                 float* __restrict__ out) {
    __shared__ ushort sWt[64][200];    // [u][k] f16, pad 192->200 (25.6 KB)
    int t = threadIdx.x;
    int gidc = blockIdx.x * 256 + t;
    if (gidc <= N_NODES) cursor[gidc] = 0u;   // reset for next replay (V=0)
    // 1536 16B chunks: row = c/24, col = (c%24)*8 ushorts; both 16B aligned.
    for (int c = t; c < 1536; c += 256) {
        int row = c / 24;
        int col = (c - row * 24) * 8;
        *(uint4v*)&sWt[row][col] = *(const uint4v*)&wt[c * 8];
    }
    __syncthreads();

    int wave = t >> 6, lane = t & 63;
    int mrow = lane & 15, quad = lane >> 4;
    int L    = blockIdx.x;
    int b    = L & 7;                  // XCD-pinned batch -> stripe b>>1
    int n0   = (L >> 3) * 64 + wave * 16;

    const uint* xs[3] = {x0, x1, x2};
    int an = n0 + mrow;
    if (an > N_NODES - 1) an = N_NODES - 1;    // clamp tail reads

    half8 af[6];
#pragma unroll
    for (int kb = 0; kb < 6; ++kb) {
        int mat = kb >> 1;
        int c_u = b * 32 + (kb & 1) * 16 + quad * 4;      // column uint index
        int q   = c_u >> 6;                               // = b>>1
        af[kb] = *(const half8*)(xs[mat] + (size_t)q * STR +
                                 (size_t)an * 64 + (c_u & 63));   // plain
    }

    float4v acc[4];
#pragma unroll
    for (int ut = 0; ut < 4; ++ut) acc[ut] = (float4v){0.f, 0.f, 0.f, 0.f};

#pragma unroll
    for (int kb = 0; kb < 6; ++kb)
#pragma unroll
        for (int ut = 0; ut < 4; ++ut)
            acc[ut] = __builtin_amdgcn_mfma_f32_16x16x32_f16(
                af[kb],
                *(const half8*)&sWt[ut * 16 + mrow][kb * 32 + quad * 8],
                acc[ut], 0, 0, 0);

#pragma unroll
    for (int ut = 0; ut < 4; ++ut) {
        float bv = bias[ut * 16 + mrow];
        int u = ut * 16 + mrow;
#pragma unroll
        for (int r = 0; r < 4; ++r) {
            int n = n0 + quad * 4 + r;
            if (n < N_NODES)
                __builtin_nontemporal_store(acc[ut][r] + bv,
                    &out[((size_t)b * N_NODES + n) * UNITS + u]);
        }
    }
}

// ---------------------------------------------------------------------------
extern "C" void kernel_launch(void* const* d_in, const int* in_sizes, int n_in,
                              void* d_out, int out_size, void* d_ws, size_t ws_size,
                              hipStream_t stream) {
    const float* inputs = (const float*)d_in[0];
    const int*   rows   = (const int*)d_in[1];
    const int*   cols   = (const int*)d_in[2];
    const float* vals   = (const float*)d_in[3];
    const float* W      = (const float*)d_in[4];
    const float* bias   = (const float*)d_in[5];
    float*       out    = (float*)d_out;
    int nnz = in_sizes[1];

    char* p = (char*)d_ws;
    auto alloc = [&](size_t bytes) {
        char* r = p;
        p += (bytes + 255) & ~(size_t)255;
        return r;
    };
    uint*   x0     = (uint*)alloc(sizeof(uint) * (size_t)N_NODES * ROW_U);
    uint*   x1     = (uint*)alloc(sizeof(uint) * (size_t)N_NODES * ROW_U);
    uint*   x2     = (uint*)alloc(sizeof(uint) * (size_t)N_NODES * ROW_U);
    uint*   cursor = (uint*)alloc(sizeof(uint) * (N_NODES + 64)); // +sentinel
    // +128 uints pad: erec2 read (base+64+lane) of the last row stays in-bounds
    uint*   edges  = (uint*)alloc(sizeof(uint) * ((size_t)N_NODES * RCAP + 128));
    ushort* wt     = (ushort*)alloc(sizeof(ushort) * 192 * 64);   // 24 KB

    // 4 dispatches, no memset (poison-base bucketing; combine resets cursor).
    k_transpose_scatter<<<5000, 256, 0, stream>>>(
        (const float4v*)inputs, x0, rows, cols, vals, cursor, edges, W, wt,
        nnz);
    k_spmm<<<5000, 256, 0, stream>>>(cursor, edges, x0, x1, nullptr, 1.0f);
    k_spmm<<<5000, 256, 0, stream>>>(cursor, edges, x1, x2, x0, 2.0f);
    k_combine<<<157 * 8, 256, 0, stream>>>(x0, x1, x2, wt, bias, cursor, out);
}

// Round 15
// 164.070 us; speedup vs baseline: 1.0794x; 1.0377x over previous
//
#include <hip/hip_runtime.h>
#include <hip/hip_fp16.h>

#define N_NODES 10000
#define BATCH   8
#define IN_SZ   64
#define UNITS   64
#define ROW_U   256            // uints per f16 row (512 f16 = 4 stripes of 64)
#define RCAP    96             // fixed per-row edge capacity (P(deg>96) ~ 1e-18)
#define STR     (N_NODES * 64) // uints per stripe (640,000)

typedef unsigned int uint;
typedef unsigned short ushort;
typedef __attribute__((ext_vector_type(8))) _Float16 half8;
typedef __attribute__((ext_vector_type(4))) float float4v;
typedef __attribute__((ext_vector_type(4))) uint uint4v;
typedef __attribute__((ext_vector_type(2))) uint uint2v;

// ---- numeric helpers -------------------------------------------------------
__device__ inline uint f2bf_bits(float f) {
    uint u = __float_as_uint(f);
    uint r = ((u >> 16) & 1u) + 0x7FFFu;
    return (u + r) >> 16;
}
__device__ inline uint pack2h(float a, float b) {
    return (uint)__half_as_ushort(__float2half(a)) |
           ((uint)__half_as_ushort(__float2half(b)) << 16);
}
__device__ inline float h_lo(uint u) {
    return __half2float(__ushort_as_half((ushort)(u & 0xFFFFu)));
}
__device__ inline float h_hi(uint u) {
    return __half2float(__ushort_as_half((ushort)(u >> 16)));
}

// ---------------------------------------------------------------------------
// EVIDENCE LEDGER (r1..r14) -- FINAL STATE:
//   F = 75.1us fixed harness [r1 vs r5]; ramp/drain ~11-14us per dispatch
//   [r10 CREP]. Steady {T ~8, S1 10.6 (= L2 traffic floor 338MB/34.5TB/s),
//   S2 9.5, C 11.75 (latency-bound: VALU 12%, HBM 29%)} [r10 PMC].
//   WINS: r8 readlane edges (-6.4); r11 nt-strip + W-prepack (-8.0);
//         r12 memset-kill (-4.0) -> 162.92 BEST.
//   FALSIFIED AXES (each tried twice, all regressed):
//     fusion/persistent: r3 597, r7 53.2-wall, r13 52.8-wall (VGPR=32 +
//       16-wave barrier coupling);
//     per-wave MLP: r14 2-row waves +7.3 (VGPR >64 -> occupancy drop);
//     combine staging: r9 no-LDS +3.2; r10 falsified recurring-fetch fix
//       beyond nt-strip.
// THIS ROUND: verbatim revert to r12 (on-file kernel is the regressed r14).
// If 162.9 reproduces, remaining budget = F (unremovable) + floor-level
// steady work + dispatch ramp/drain that three structural attacks failed
// to compress => ROOFLINE.
// ---------------------------------------------------------------------------

// ---------------------------------------------------------------------------
// k_transpose_scatter: float4-in / uint2-out transpose + edge scatter with
// poison-base slots + one-time W prepack. Grid <<<5000, 256>>> (1.28M thr).
// ---------------------------------------------------------------------------
__global__ __launch_bounds__(256) void k_transpose_scatter(
    const float4v* __restrict__ in4, uint* __restrict__ x0,
    const int* __restrict__ rows, const int* __restrict__ cols,
    const float* __restrict__ vals, uint* __restrict__ cursor,
    uint* __restrict__ edges, const float* __restrict__ W,
    ushort* __restrict__ wt, int nnz) {
    int gid = blockIdx.x * 256 + threadIdx.x;      // 1,280,000 total
    uint V = cursor[N_NODES];           // uniform poison base (or 0 on replay)
    if (gid < nnz) {
        int  r   = rows[gid];
        uint pos = atomicAdd(&cursor[r], 1u) - V;   // slot 0..deg-1, wrap-safe
        edges[r * RCAP + pos] = (uint)cols[gid] | (f2bf_bits(vals[gid]) << 16);
    }
    if (gid < 192 * 64) {               // one-time W prepack (sWt-linear)
        int u   = gid / 192;
        int col = gid - u * 192;        // = m*64 + i
        int m   = col >> 6, i = col & 63;
        wt[gid] = (ushort)__half_as_ushort(__float2half(W[(i * 3 + m) * 64 + u]));
    }
    int i4 = gid & 15;          // 4-channel chunk
    int b  = (gid >> 4) & 7;    // batch
    int n  = gid >> 7;          // node
    float4v v = __builtin_nontemporal_load(
        &in4[((size_t)b * N_NODES + n) * 16 + i4]);
    int c_u = b * 32 + i4 * 2;  // uint index within 256-uint row
    int q   = c_u >> 6;         // stripe (= b>>1)
    uint2v pk;
    pk.x = pack2h(v.x, v.y);
    pk.y = pack2h(v.z, v.w);
    *(uint2v*)(x0 + (size_t)q * STR + (size_t)n * 64 + (c_u & 63)) = pk;
}

// ---- spmm inner machinery (r8, proven) -------------------------------------
#define READE(EP, KB)                                                         \
    {                                                                         \
        uint _es = ((KB) < 8) ? erec : erec2;                                 \
        int  _i0 = (((KB) * 8) & 63);                                         \
        _Pragma("unroll") for (int jj = 0; jj < 8; ++jj)                      \
            EP[jj] = __builtin_amdgcn_readlane(_es, _i0 + jj);                \
    }

#define GATHERX(XR, EP)                                                       \
    _Pragma("unroll") for (int jj = 0; jj < 8; ++jj) {                        \
        uint c = EP[jj] & 0x3FFFu;                                            \
        if (c > N_NODES - 1) c = N_NODES - 1; /* s_min (garbage slots) */     \
        XR[jj] = xq[c * 64u + lane];          /* SALU idx + saddr gather */   \
    }

#define FMA8(EP, XR)                                                          \
    _Pragma("unroll") for (int jj = 0; jj < 8; ++jj) {                        \
        float vj = __uint_as_float(EP[jj] & 0xFFFF0000u); /* SALU decode */   \
        a0 += vj * h_lo(XR[jj]); /* v_fma_mix_f32 */                          \
        a1 += vj * h_hi(XR[jj]); /* v_fma_mix_f32 */                          \
    }

// ---------------------------------------------------------------------------
// k_spmm: one WAVE per (row, stripe); readlane edge path; cnt = cursor - V.
// Grid <<<N_NODES, 256>>>; stripe q = (L&7)>>1 pinned to XCD pair {2q,2q+1}.
// ---------------------------------------------------------------------------
__global__ __launch_bounds__(256) void k_spmm(const uint* __restrict__ cursor,
                                              const uint* __restrict__ edges,
                                              const uint* __restrict__ xin,
                                              uint* __restrict__ xout,
                                              const uint* __restrict__ xsub,
                                              float scale) {
    int L    = blockIdx.x;              // 10000 blocks
    int q    = (L & 7) >> 1;            // stripe pinned to XCD pair {2q,2q+1}
    int rb   = ((L >> 3) << 1) | (L & 1);   // 0..2499, bijective per stripe
    int wave = threadIdx.x >> 6;
    uint lane = threadIdx.x & 63;
    int row  = rb * 4 + wave;

    const uint* xq = xin + (size_t)q * STR;
    int base = row * RCAP;
    uint V   = cursor[N_NODES];
    int cnt  = (int)__builtin_amdgcn_readfirstlane(cursor[row] - V);
    int nblk = (cnt + 7) >> 3;          // >= 1 (diagonal guarantees cnt >= 1)

    uint erec = edges[base + (int)lane];
    if ((int)lane >= cnt) erec &= 0x3FFFu;          // v_cndmask
    uint erec2 = 0;
    if (cnt > 64) {                                  // uniform branch, rare
        erec2 = edges[base + 64 + (int)lane];
        if ((int)lane + 64 >= cnt) erec2 &= 0x3FFFu;
    }

    uint sx = 0;
    if (xsub) sx = xsub[(size_t)q * STR + (size_t)row * 64 + lane];   // plain

    float a0 = 0.f, a1 = 0.f;
    uint epA[8], epB[8], xA[8], xB[8];
    READE(epA, 0);
    GATHERX(xA, epA);
    int k = 0;
    for (; k + 2 <= nblk; k += 2) {
        READE(epB, k + 1);                // register-only: no lgkm chain
        GATHERX(xB, epB);                 // gathers in flight
        FMA8(epA, xA);                    // consume stage k
        if (k + 2 < nblk) {
            READE(epA, k + 2);
            GATHERX(xA, epA);
        }
        FMA8(epB, xB);                    // consume stage k+1
    }
    if (k < nblk) FMA8(epA, xA);          // odd block count

    float o0 = scale * a0, o1 = scale * a1;
    if (xsub) {
        o0 -= h_lo(sx);
        o1 -= h_hi(sx);
    }
    // plain store: keep the line L2-resident for spmm2 gathers / combine
    xout[(size_t)q * STR + (size_t)row * 64 + lane] = pack2h(o0, o1);
}

// ---------------------------------------------------------------------------
// k_combine (MFMA f16): LDS-staged W via b128 copies from prepacked wt;
// plain af loads; cursor re-zero for no-poison replays.
// Grid <<<157*8, 256>>>; b = L&7 pins batch -> stripe q=b>>1.
// ---------------------------------------------------------------------------
__global__ __launch_bounds__(256) void k_combine(const uint* __restrict__ x0,
                                                 const uint* __restrict__ x1,
                                                 const uint* __restrict__ x2,
                                                 const ushort* __restrict__ wt,
                                                 const float* __restrict__ bias,
                                                 uint* __restrict__ cursor,
                                                 float* __restrict__ out) {
    __shared__ ushort sWt[64][200];    // [u][k] f16, pad 192->200 (25.6 KB)
    int t = threadIdx.x;
    int gidc = blockIdx.x * 256 + t;
    if (gidc <= N_NODES) cursor[gidc] = 0u;   // reset for next replay (V=0)
    // 1536 16B chunks: row = c/24, col = (c%24)*8 ushorts; both 16B aligned.
    for (int c = t; c < 1536; c += 256) {
        int row = c / 24;
        int col = (c - row * 24) * 8;
        *(uint4v*)&sWt[row][col] = *(const uint4v*)&wt[c * 8];
    }
    __syncthreads();

    int wave = t >> 6, lane = t & 63;
    int mrow = lane & 15, quad = lane >> 4;
    int L    = blockIdx.x;
    int b    = L & 7;                  // XCD-pinned batch -> stripe b>>1
    int n0   = (L >> 3) * 64 + wave * 16;

    const uint* xs[3] = {x0, x1, x2};
    int an = n0 + mrow;
    if (an > N_NODES - 1) an = N_NODES - 1;    // clamp tail reads

    half8 af[6];
#pragma unroll
    for (int kb = 0; kb < 6; ++kb) {
        int mat = kb >> 1;
        int c_u = b * 32 + (kb & 1) * 16 + quad * 4;      // column uint index
        int q   = c_u >> 6;                               // = b>>1
        af[kb] = *(const half8*)(xs[mat] + (size_t)q * STR +
                                 (size_t)an * 64 + (c_u & 63));   // plain
    }

    float4v acc[4];
#pragma unroll
    for (int ut = 0; ut < 4; ++ut) acc[ut] = (float4v){0.f, 0.f, 0.f, 0.f};

#pragma unroll
    for (int kb = 0; kb < 6; ++kb)
#pragma unroll
        for (int ut = 0; ut < 4; ++ut)
            acc[ut] = __builtin_amdgcn_mfma_f32_16x16x32_f16(
                af[kb],
                *(const half8*)&sWt[ut * 16 + mrow][kb * 32 + quad * 8],
                acc[ut], 0, 0, 0);

#pragma unroll
    for (int ut = 0; ut < 4; ++ut) {
        float bv = bias[ut * 16 + mrow];
        int u = ut * 16 + mrow;
#pragma unroll
        for (int r = 0; r < 4; ++r) {
            int n = n0 + quad * 4 + r;
            if (n < N_NODES)
                __builtin_nontemporal_store(acc[ut][r] + bv,
                    &out[((size_t)b * N_NODES + n) * UNITS + u]);
        }
    }
}

// ---------------------------------------------------------------------------
extern "C" void kernel_launch(void* const* d_in, const int* in_sizes, int n_in,
                              void* d_out, int out_size, void* d_ws, size_t ws_size,
                              hipStream_t stream) {
    const float* inputs = (const float*)d_in[0];
    const int*   rows   = (const int*)d_in[1];
    const int*   cols   = (const int*)d_in[2];
    const float* vals   = (const float*)d_in[3];
    const float* W      = (const float*)d_in[4];
    const float* bias   = (const float*)d_in[5];
    float*       out    = (float*)d_out;
    int nnz = in_sizes[1];

    char* p = (char*)d_ws;
    auto alloc = [&](size_t bytes) {
        char* r = p;
        p += (bytes + 255) & ~(size_t)255;
        return r;
    };
    uint*   x0     = (uint*)alloc(sizeof(uint) * (size_t)N_NODES * ROW_U);
    uint*   x1     = (uint*)alloc(sizeof(uint) * (size_t)N_NODES * ROW_U);
    uint*   x2     = (uint*)alloc(sizeof(uint) * (size_t)N_NODES * ROW_U);
    uint*   cursor = (uint*)alloc(sizeof(uint) * (N_NODES + 64)); // +sentinel
    // +128 uints pad: erec2 read (base+64+lane) of the last row stays in-bounds
    uint*   edges  = (uint*)alloc(sizeof(uint) * ((size_t)N_NODES * RCAP + 128));
    ushort* wt     = (ushort*)alloc(sizeof(ushort) * 192 * 64);   // 24 KB

    // NO memset: poison-base bucketing (V = cursor[N_NODES]) + combine's
    // cursor re-zero make the pipeline self-consistent. 4 dispatches.
    k_transpose_scatter<<<5000, 256, 0, stream>>>(
        (const float4v*)inputs, x0, rows, cols, vals, cursor, edges, W, wt,
        nnz);
    k_spmm<<<N_NODES, 256, 0, stream>>>(cursor, edges, x0, x1, nullptr, 1.0f);
    k_spmm<<<N_NODES, 256, 0, stream>>>(cursor, edges, x1, x2, x0, 2.0f);
    k_combine<<<157 * 8, 256, 0, stream>>>(x0, x1, x2, wt, bias, cursor, out);
}